// Round 2
// baseline (1239.244 us; speedup 1.0000x reference)
//
#include <hip/hip_runtime.h>
#include <math.h>

#define EPSC 1e-8f
#define TOPK 5

typedef _Float16 half8_t __attribute__((ext_vector_type(8)));
typedef float f32x4 __attribute__((ext_vector_type(4)));

__device__ __forceinline__ bool better(float va, int ia, float vb, int ib) {
    return (va > vb) || (va == vb && ia < ib);
}

// insert (v,gi) into sorted-desc top-5 (lv,li)
__device__ __forceinline__ void ins5(float v, int gi, float lv[TOPK], int li[TOPK]) {
    if (better(v, gi, lv[4], li[4])) {
        lv[4] = v; li[4] = gi;
#pragma unroll
        for (int p = 4; p > 0; --p) {
            if (better(lv[p], li[p], lv[p - 1], li[p - 1])) {
                float tv = lv[p]; lv[p] = lv[p - 1]; lv[p - 1] = tv;
                int ti = li[p]; li[p] = li[p - 1]; li[p - 1] = ti;
            }
        }
    }
}

// ---------------- center = mean(spatial_weights, axis=0) ----------------
__global__ void k_center(const float* __restrict__ sw, int H, float* __restrict__ center) {
    int tid = threadIdx.x;  // 64
    float sx = 0.f, sy = 0.f;
    for (int r = tid; r < H; r += 64) { sx += sw[2 * r]; sy += sw[2 * r + 1]; }
    for (int o = 32; o > 0; o >>= 1) { sx += __shfl_down(sx, o); sy += __shfl_down(sy, o); }
    if (tid == 0) { center[0] = sx / (float)H; center[1] = sy / (float)H; }
}

// ---------------- normalize queries + split to f16 hi/lo, frag-CONTIGUOUS layout ----------------
// For (kc, w, lane): 8 frags (rt0hi, rt0lo, rt1hi, ... rt3lo) of 8 f16 each = 128 B contiguous.
// idx = (((kc*4 + w)*64 + lane)*64) + rt*16 + plane*8 + j
//   where for query b: qt=b>>4, w=qt>>2, rt=qt&3, nl=b&15; for dim d: kc=d>>5, quad=(d&31)>>3, j=d&7;
//   lane = quad*16 + nl.
__global__ void k_qprep(const float* __restrict__ q, _Float16* __restrict__ Aglob, int B, int D) {
    int b = blockIdx.x;
    int tid = threadIdx.x;  // 128
    float ss = 0.f;
    for (int d = tid; d < D; d += 128) { float v = q[(size_t)b * D + d]; ss = fmaf(v, v, ss); }
    for (int o = 32; o > 0; o >>= 1) ss += __shfl_down(ss, o);
    __shared__ float w2[2];
    if ((tid & 63) == 0) w2[tid >> 6] = ss;
    __syncthreads();
    float inv = 1.f / fmaxf(sqrtf(w2[0] + w2[1]), EPSC);
    int qt = b >> 4, nl = b & 15;
    int w = qt >> 2, rt = qt & 3;
    for (int d = tid; d < D; d += 128) {
        float v = q[(size_t)b * D + d] * inv;
        _Float16 hi = (_Float16)v;
        _Float16 lo = (_Float16)(v - (float)hi);
        int kc = d >> 5, r = d & 31, quad = r >> 3, j = r & 7;
        int lane = quad * 16 + nl;
        size_t idx = (((size_t)kc * 4 + w) * 64 + lane) * 64 + rt * 16 + j;
        Aglob[idx] = hi;
        Aglob[idx + 8] = lo;
    }
}

// convert 8 fp32 -> f16 hi/lo planes + fused sum-of-squares, write to LDS
__device__ __forceinline__ void convwrite(float4 v0, float4 v1, _Float16* Bh, _Float16* Bl,
                                          int off, float& ss) {
    float vv[8] = {v0.x, v0.y, v0.z, v0.w, v1.x, v1.y, v1.z, v1.w};
    half8_t hv, lov;
#pragma unroll
    for (int j = 0; j < 8; ++j) {
        float f = vv[j];
        ss = fmaf(f, f, ss);
        _Float16 h = (_Float16)f;
        hv[j] = h;
        lov[j] = (_Float16)(f - (float)h);
    }
    *(half8_t*)(Bh + off) = hv;
    *(half8_t*)(Bl + off) = lov;
}

// ---------------- main: split-f16 MFMA sim GEMM + fused norms + per-row top-5 ----------------
// grid: ceil(M/128), 256 threads (4 waves). Block: 256 queries x 128 mem rows (2 chunks of 64).
// A-frags read direct from global (L2-resident). B double-buffered in LDS with reg prefetch.
__launch_bounds__(256, 3)
__global__ void k_sim_topk(const _Float16* __restrict__ Aglob, const float* __restrict__ mem,
                           const float* __restrict__ coords, const float* __restrict__ center,
                           float* __restrict__ candV, int* __restrict__ candI,
                           int M, int D) {
    __shared__ __align__(16) char smem[36352];
    _Float16* Bbuf = (_Float16*)smem;        // 2 bufs x (Bh 2048 + Bl 2048 f16) = 16384 B
    float* Cs = (float*)smem;                // epilogue overlay: 4 waves x 32 x 68 fp32 = 34816 B
    float* ssbuf  = (float*)(smem + 34816);  // 256 fp32
    float* colinv = ssbuf + 256;             // 64
    float* colact = colinv + 64;             // 64

    const int tid = threadIdx.x;
    const int lane = tid & 63, w = tid >> 6;
    const int nB = tid >> 2, qB = tid & 3;   // B staging: mem-row nB (0..63), k-octet qB
    const int KCH = D >> 5;
    const int n0 = blockIdx.x * 128;
    const float cx = center[0], cy = center[1];
    const int quad = lane >> 4, c15 = lane & 15;
    const int rr = lane & 31, hh = lane >> 5;
    const int woff = ((nB >> 4) * 64 + qB * 16 + (nB & 15)) * 8;  // f16 offset in B plane

    float lv[TOPK]; int li[TOPK];
#pragma unroll
    for (int k = 0; k < TOPK; ++k) { lv[k] = -INFINITY; li[k] = 0x7fffffff; }

    for (int ch = 0; ch < 2; ++ch) {
        const int base = n0 + ch * 64;
        const int brow = base + nB;
        const bool bvalid = brow < M;
        const float* mrow = mem + (size_t)brow * D;
        f32x4 acc[4][4];
#pragma unroll
        for (int rt = 0; rt < 4; ++rt)
#pragma unroll
            for (int ct = 0; ct < 4; ++ct) acc[rt][ct] = (f32x4){0.f, 0.f, 0.f, 0.f};
        float ss = 0.f;

        // prologue: stage B for kc=0 into buf 0
        {
            float4 v0 = {0.f, 0.f, 0.f, 0.f}, v1 = {0.f, 0.f, 0.f, 0.f};
            if (bvalid) {
                const float* p0 = mrow + qB * 8;
                v0 = *(const float4*)p0;
                v1 = *(const float4*)(p0 + 4);
            }
            convwrite(v0, v1, Bbuf, Bbuf + 2048, woff, ss);
        }

        for (int kc = 0; kc < KCH; ++kc) {
            const int p = kc & 1;
            __syncthreads();  // buf[p] ready; prev-iter reads of buf[p^1] done
            // A fragments direct from global (one base, imm offsets 0..120B)
            half8_t ah[4], al[4];
            const _Float16* aptr = Aglob + (((size_t)kc * 4 + w) * 64 + lane) * 64;
#pragma unroll
            for (int rt = 0; rt < 4; ++rt) {
                ah[rt] = *(const half8_t*)(aptr + rt * 16);
                al[rt] = *(const half8_t*)(aptr + rt * 16 + 8);
            }
            // prefetch next-kc B (HBM latency hides under MFMA phase below)
            float4 n0v = {0.f, 0.f, 0.f, 0.f}, n1v = {0.f, 0.f, 0.f, 0.f};
            if (kc + 1 < KCH && bvalid) {
                const float* pn = mrow + (kc + 1) * 32 + qB * 8;
                n0v = *(const float4*)pn;
                n1v = *(const float4*)(pn + 4);
            }
            // B fragments (streamed per ct) + MFMA (hh, hl, lh products)
            const _Float16* Bh = Bbuf + p * 4096;
            const _Float16* Bl = Bh + 2048;
#pragma unroll
            for (int ct = 0; ct < 4; ++ct) {
                half8_t bh = *(const half8_t*)(Bh + (ct * 64 + lane) * 8);
                half8_t bl = *(const half8_t*)(Bl + (ct * 64 + lane) * 8);
#pragma unroll
                for (int rt = 0; rt < 4; ++rt) {
                    acc[rt][ct] = __builtin_amdgcn_mfma_f32_16x16x32_f16(ah[rt], bh, acc[rt][ct], 0, 0, 0);
                    acc[rt][ct] = __builtin_amdgcn_mfma_f32_16x16x32_f16(ah[rt], bl, acc[rt][ct], 0, 0, 0);
                    acc[rt][ct] = __builtin_amdgcn_mfma_f32_16x16x32_f16(al[rt], bh, acc[rt][ct], 0, 0, 0);
                }
            }
            // convert + write next B into buf[p^1] (consumes prefetch)
            if (kc + 1 < KCH) {
                _Float16* Bhn = Bbuf + (p ^ 1) * 4096;
                convwrite(n0v, n1v, Bhn, Bhn + 2048, woff, ss);
            }
        }

        // column stats
        ssbuf[tid] = ss;
        __syncthreads();  // all B-frag reads done before Cs overlay; ssbuf visible
        if (tid < 64) {
            float s = ssbuf[tid * 4] + ssbuf[tid * 4 + 1] + ssbuf[tid * 4 + 2] + ssbuf[tid * 4 + 3];
            colinv[tid] = 1.f / fmaxf(sqrtf(s), EPSC);
            int m = base + tid;
            float act = -INFINITY;
            if (m < M) {
                float dx = coords[2 * (size_t)m] - cx;
                float dy = coords[2 * (size_t)m + 1] - cy;
                act = 1.f / (1.f + sqrtf(dx * dx + dy * dy));
            }
            colact[tid] = act;
        }
        __syncthreads();

        // epilogue: two 32-row passes; per pass each row scanned by 2 lanes (32 cols each),
        // sorted-5 lists merged via shfl_xor(32) with SNAPSHOT (both lanes mutate tv5 —
        // must capture partner's full list before inserting). Owner lane absorbs.
        float* Cw = Cs + w * (32 * 68);
#pragma unroll
        for (int ps = 0; ps < 2; ++ps) {
#pragma unroll
            for (int rt2 = 0; rt2 < 2; ++rt2) {
                const int rt = 2 * ps + rt2;
#pragma unroll
                for (int ct = 0; ct < 4; ++ct) {
                    const int c = ct * 16 + c15;
                    const float inv = colinv[c], act = colact[c];
#pragma unroll
                    for (int i = 0; i < 4; ++i) {
                        Cw[(rt2 * 16 + quad * 4 + i) * 68 + c] = fmaf(acc[rt][ct][i], inv, act);
                    }
                }
            }
            // same-wave write->read: no barrier needed
            float tv5[TOPK]; int ti5[TOPK];
#pragma unroll
            for (int k = 0; k < TOPK; ++k) { tv5[k] = -INFINITY; ti5[k] = 0x7fffffff; }
            const float* Crow = Cw + rr * 68 + hh * 32;
            for (int j = 0; j < 32; ++j) {
                const int cc = (j + lane) & 31;
                ins5(Crow[cc], base + hh * 32 + cc, tv5, ti5);
            }
            // snapshot partner's list FIRST (both sides mutate during merge)
            float pv[TOPK]; int pi[TOPK];
#pragma unroll
            for (int k = 0; k < TOPK; ++k) {
                pv[k] = __shfl_xor(tv5[k], 32);
                pi[k] = __shfl_xor(ti5[k], 32);
            }
#pragma unroll
            for (int k = 0; k < TOPK; ++k) ins5(pv[k], pi[k], tv5, ti5);
            if (hh == ps) {  // owner lane: query offset = ps*32 + rr == lane
#pragma unroll
                for (int k = 0; k < TOPK; ++k) ins5(tv5[k], ti5[k], lv, li);
            }
        }
        __syncthreads();  // epilogue reads done before next chunk restages Bbuf (overlaps Cs)
    }
    // per-q candidates: q = w*64 + lane
    size_t cb = ((size_t)blockIdx.x * 256 + (w * 64 + lane)) * TOPK;
#pragma unroll
    for (int k = 0; k < TOPK; ++k) { candV[cb + k] = lv[k]; candI[cb + k] = li[k]; }
}

// ---------------- merge per-tile candidates -> global top-5 (sorted desc) ----------------
__global__ void k_merge(const float* __restrict__ candV, const int* __restrict__ candI,
                        int ntiles, int B, int* __restrict__ topk) {
    int b = blockIdx.x;
    int tid = threadIdx.x;  // 256
    float lv[TOPK]; int li[TOPK];
#pragma unroll
    for (int k = 0; k < TOPK; ++k) { lv[k] = -INFINITY; li[k] = 0x7fffffff; }
    for (int t = tid; t < ntiles; t += 256) {
        size_t base = ((size_t)t * B + b) * TOPK;
#pragma unroll
        for (int k = 0; k < TOPK; ++k) {
            float v = candV[base + k]; int gi = candI[base + k];
            if (better(v, gi, lv[4], li[4])) {
                lv[4] = v; li[4] = gi;
#pragma unroll
                for (int p = 4; p > 0; --p) {
                    if (better(lv[p], li[p], lv[p - 1], li[p - 1])) {
                        float tv = lv[p]; lv[p] = lv[p - 1]; lv[p - 1] = tv;
                        int ti = li[p]; li[p] = li[p - 1]; li[p - 1] = ti;
                    }
                }
            }
        }
    }
    __shared__ float sv[256 * TOPK];
    __shared__ int si[256 * TOPK];
#pragma unroll
    for (int k = 0; k < TOPK; ++k) { sv[tid * TOPK + k] = lv[k]; si[tid * TOPK + k] = li[k]; }
    __syncthreads();
    __shared__ float rv[256];
    __shared__ int ri[256], rp[256];
    for (int round = 0; round < TOPK; ++round) {
        float bv = -INFINITY; int bi = 0x7fffffff, bp = -1;
        for (int p = tid; p < 256 * TOPK; p += 256) {
            if (better(sv[p], si[p], bv, bi)) { bv = sv[p]; bi = si[p]; bp = p; }
        }
        rv[tid] = bv; ri[tid] = bi; rp[tid] = bp;
        __syncthreads();
        for (int st = 128; st > 0; st >>= 1) {
            if (tid < st) {
                if (better(rv[tid + st], ri[tid + st], rv[tid], ri[tid])) {
                    rv[tid] = rv[tid + st]; ri[tid] = ri[tid + st]; rp[tid] = rp[tid + st];
                }
            }
            __syncthreads();
        }
        if (tid == 0) {
            topk[b * TOPK + round] = ri[0];
            sv[rp[0]] = -INFINITY;
            si[rp[0]] = 0x7fffffff;
        }
        __syncthreads();
    }
}

// ---------------- gather RNN inputs: INP[b*6+t][D] ----------------
__global__ void k_gather(const float* __restrict__ q, const float* __restrict__ mem,
                         const int* __restrict__ topk, float* __restrict__ inp, int D) {
    int r = blockIdx.x;          // 0..B*6-1
    int b = r / 6, t = r - b * 6;
    int tid = threadIdx.x;       // 96 (D/4)
    const float* src = (t == 0) ? (q + (size_t)b * D)
                                : (mem + (size_t)topk[b * TOPK + (t - 1)] * D);
    *(float4*)&inp[(size_t)r * D + tid * 4] = *(const float4*)&src[tid * 4];
}

// ---------------- generic 64x64-tile fp32 GEMM tail: C = act(A @ W^T + bias [+ addv]) ----------------
// mode 0: dst = v                      (xproj)
// mode 1: dst = sigmoid(v)             (gate)
// mode 2: dst = tanh(v + addv)         (rnn step; skipA=1 => h_prev = 0)
// mode 3: dst = g*tanh(v+addv) + (1-g)*xp0   (final rnn + combine)
__launch_bounds__(256)
__global__ void k_tail_gemm(const float* __restrict__ A, const float* __restrict__ W,
                            const float* __restrict__ bias, const float* __restrict__ addv,
                            int addv_stride, const float* __restrict__ gatep,
                            const float* __restrict__ xp0, int xp0_stride,
                            float* __restrict__ dst, int K, int ldc, int mode, int skipA) {
    __shared__ float As[16 * 68], Ws[16 * 68];
    const int r0 = blockIdx.x * 64, c0 = blockIdx.y * 64;
    const int tid = threadIdx.x;
    float acc[4][4];
#pragma unroll
    for (int i = 0; i < 4; ++i)
#pragma unroll
        for (int j = 0; j < 4; ++j) acc[i][j] = 0.f;
    if (!skipA) {
        const int lr = tid >> 2, lk4 = (tid & 3) * 4;
        for (int k0 = 0; k0 < K; k0 += 16) {
            __syncthreads();
            float4 av = *(const float4*)&A[(size_t)(r0 + lr) * K + k0 + lk4];
            float4 wv = *(const float4*)&W[(size_t)(c0 + lr) * K + k0 + lk4];
            As[(lk4 + 0) * 68 + lr] = av.x; As[(lk4 + 1) * 68 + lr] = av.y;
            As[(lk4 + 2) * 68 + lr] = av.z; As[(lk4 + 3) * 68 + lr] = av.w;
            Ws[(lk4 + 0) * 68 + lr] = wv.x; Ws[(lk4 + 1) * 68 + lr] = wv.y;
            Ws[(lk4 + 2) * 68 + lr] = wv.z; Ws[(lk4 + 3) * 68 + lr] = wv.w;
            __syncthreads();
#pragma unroll
            for (int k = 0; k < 16; ++k) {
                float4 a4 = *(float4*)&As[k * 68 + (tid >> 4) * 4];
                float4 b4 = *(float4*)&Ws[k * 68 + (tid & 15) * 4];
                float a[4] = {a4.x, a4.y, a4.z, a4.w};
                float bb[4] = {b4.x, b4.y, b4.z, b4.w};
#pragma unroll
                for (int i = 0; i < 4; ++i)
#pragma unroll
                    for (int j = 0; j < 4; ++j) acc[i][j] = fmaf(a[i], bb[j], acc[i][j]);
            }
        }
    }
    const int tr = (tid >> 4) * 4, tc = (tid & 15) * 4;
#pragma unroll
    for (int i = 0; i < 4; ++i) {
        int r = r0 + tr + i;
#pragma unroll
        for (int j = 0; j < 4; ++j) {
            int c = c0 + tc + j;
            float v = acc[i][j] + bias[c];
            if (mode >= 2) v += addv[(size_t)r * addv_stride + c];
            float res;
            if (mode == 0) res = v;
            else if (mode == 1) res = 1.f / (1.f + expf(-v));
            else if (mode == 2) res = tanhf(v);
            else {
                float hn = tanhf(v);
                float g = gatep[(size_t)r * ldc + c];
                res = g * hn + (1.f - g) * xp0[(size_t)r * xp0_stride + c];
            }
            dst[(size_t)r * ldc + c] = res;
        }
    }
}

extern "C" void kernel_launch(void* const* d_in, const int* in_sizes, int n_in,
                              void* d_out, int out_size, void* d_ws, size_t ws_size,
                              hipStream_t stream) {
    const float* query  = (const float*)d_in[0];
    const float* mem    = (const float*)d_in[1];
    const float* coords = (const float*)d_in[2];
    const float* sw     = (const float*)d_in[3];
    const float* W_ih   = (const float*)d_in[4];
    const float* b_ih   = (const float*)d_in[5];
    const float* W_hh   = (const float*)d_in[6];
    const float* b_hh   = (const float*)d_in[7];
    const float* gate_W = (const float*)d_in[8];
    const float* gate_b = (const float*)d_in[9];

    const int H = in_sizes[5];           // 512
    const int D = in_sizes[4] / H;       // 384
    const int B = in_sizes[0] / D;       // 256
    const int M = in_sizes[1] / D;       // 200000
    const int KCH = D >> 5;
    const int ntiles = (M + 127) / 128;  // 1563

    float* Wf = (float*)d_ws;
    size_t off = 0;
    _Float16* Aglob = (_Float16*)Wf;     off += (size_t)2 * 16 * KCH * 512 / 2;  // f16 elems /2 = floats
    float* center = Wf + off; off += 4;
    float* candV  = Wf + off; off += (size_t)ntiles * B * TOPK;
    int*   candI  = (int*)(Wf + off); off += (size_t)ntiles * B * TOPK;
    int*   topk   = (int*)(Wf + off); off += B * TOPK;
    float* inp    = Wf + off; off += (size_t)B * 6 * D;
    float* xp     = Wf + off; off += (size_t)B * 6 * H;
    float* gate   = Wf + off; off += (size_t)B * H;
    float* hA     = Wf + off; off += (size_t)B * H;
    float* hB     = Wf + off; off += (size_t)B * H;

    k_center<<<1, 64, 0, stream>>>(sw, H, center);
    k_qprep<<<B, 128, 0, stream>>>(query, Aglob, B, D);
    k_sim_topk<<<ntiles, 256, 0, stream>>>(Aglob, mem, coords, center, candV, candI, M, D);
    k_merge<<<B, 256, 0, stream>>>(candV, candI, ntiles, B, topk);
    k_gather<<<B * 6, D / 4, 0, stream>>>(query, mem, topk, inp, D);
    // xp[b*6+t][H] = INP @ W_ih^T + b_ih
    k_tail_gemm<<<dim3(B * 6 / 64, H / 64), 256, 0, stream>>>(
        inp, W_ih, b_ih, nullptr, 0, nullptr, nullptr, 0, xp, D, H, 0, 0);
    // gate = sigmoid(q @ gate_W^T + gate_b)
    k_tail_gemm<<<dim3(B / 64, H / 64), 256, 0, stream>>>(
        query, gate_W, gate_b, nullptr, 0, nullptr, nullptr, 0, gate, D, H, 1, 0);
    // RNN: h_t = tanh(xp_t + h_{t-1} @ W_hh^T + b_hh); ping-pong hA/hB
    float* hprev = hA; float* hnext = hB;
    for (int t = 0; t <= TOPK; ++t) {
        int first = (t == 0), last = (t == TOPK);
        k_tail_gemm<<<dim3(B / 64, H / 64), 256, 0, stream>>>(
            hprev, W_hh, b_hh, xp + (size_t)t * H, 6 * H, gate, xp, 6 * H,
            last ? (float*)d_out : hnext, H, H, last ? 3 : 2, first);
        float* tmp = hprev; hprev = hnext; hnext = tmp;
    }
}